// Round 2
// baseline (482.732 us; speedup 1.0000x reference)
//
#include <hip/hip_runtime.h>
#include <cmath>

#define D 160
#define DD (D*D)          // 25600
#define NVOX (D*D*D)
#define BIGV (NVOX + 2)
#define NBINS 4096
#define HALF 16
#define RGRID 800         // rotate-pass blocks = DD/32, also hist partial count
#define SGRID 1000        // sweep blocks (512 thr, 8 cells/thread)

// ---------------------------------------------------------------------------
// Rotate-pipeline box filter (window 32, 'same'), INT packed path.
// ---------------------------------------------------------------------------
template<int MODE>
__global__ __launch_bounds__(256) void box_rot_int_kernel(
    const void* __restrict__ vin, unsigned* __restrict__ out)
{
    __shared__ unsigned tin[32][161];
    __shared__ unsigned filt[160][33];
    int L0 = blockIdx.x * 32;
    size_t base = (size_t)L0 * D;

    if (MODE == 0) {
        const float4* s4 = (const float4*)((const float*)vin + base);
        for (int i = threadIdx.x; i < 32 * (D / 4); i += 256) {
            float4 v = s4[i];
            int e = i * 4, r = e / D, c = e - r * D;
            float rr;
            rr = rintf(v.x); tin[r][c]   = (rr==0.f) | ((rr==1.f)?0x10000u:0u);
            rr = rintf(v.y); tin[r][c+1] = (rr==0.f) | ((rr==1.f)?0x10000u:0u);
            rr = rintf(v.z); tin[r][c+2] = (rr==0.f) | ((rr==1.f)?0x10000u:0u);
            rr = rintf(v.w); tin[r][c+3] = (rr==0.f) | ((rr==1.f)?0x10000u:0u);
        }
    } else {
        const uint4* s4 = (const uint4*)((const unsigned*)vin + base);
        for (int i = threadIdx.x; i < 32 * (D / 4); i += 256) {
            uint4 v = s4[i];
            int e = i * 4, r = e / D, c = e - r * D;
            tin[r][c] = v.x; tin[r][c+1] = v.y; tin[r][c+2] = v.z; tin[r][c+3] = v.w;
        }
    }
    __syncthreads();

    {
        int r = threadIdx.x & 31, s = threadIdx.x >> 5;
        int i0 = 20 * s;
        const unsigned* ln = tin[r];
        unsigned sum = 0u;
        int jlo = i0 - 16; if (jlo < 0) jlo = 0;
        int jhi = i0 + 15; if (jhi > D - 1) jhi = D - 1;
        for (int j = jlo; j <= jhi; ++j) sum += ln[j];
        #pragma unroll 4
        for (int k = 0; k < 20; ++k) {
            int i = i0 + k;
            filt[i][r] = sum;
            int add = i + 16, rem = i - 16;
            if (add <= D - 1) sum += ln[add];
            if (rem >= 0)     sum -= ln[rem];
        }
    }
    __syncthreads();

    int r = threadIdx.x & 31;
    for (int c = (threadIdx.x >> 5); c < D; c += 8)
        out[(size_t)c * DD + L0 + r] = filt[c][r];
}

// ---------------------------------------------------------------------------
// Rotate box filter, FLOAT path, pass 1: fuses the lsize*valid gather.
// ---------------------------------------------------------------------------
__global__ __launch_bounds__(256) void box_rot_f32_g_kernel(
    const int* __restrict__ lab, const int* __restrict__ cnt,
    const unsigned* __restrict__ cwp, float* __restrict__ out)
{
    __shared__ float tin[32][161];
    __shared__ float filt[160][33];
    int L0 = blockIdx.x * 32;
    size_t base = (size_t)L0 * D;

    const int4*  lab4 = (const int4*)(lab + base);
    const uint4* cw4  = (const uint4*)(cwp + base);
    for (int i = threadIdx.x; i < 32 * (D / 4); i += 256) {
        int4 l = lab4[i];
        uint4 cw = cw4[i];
        int e = i * 4, r = e / D, c = e - r * D;
        tin[r][c]   = (l.x != BIGV && (cw.x >> 16) > 100u) ? (float)cnt[l.x] : 0.f;
        tin[r][c+1] = (l.y != BIGV && (cw.y >> 16) > 100u) ? (float)cnt[l.y] : 0.f;
        tin[r][c+2] = (l.z != BIGV && (cw.z >> 16) > 100u) ? (float)cnt[l.z] : 0.f;
        tin[r][c+3] = (l.w != BIGV && (cw.w >> 16) > 100u) ? (float)cnt[l.w] : 0.f;
    }
    __syncthreads();

    {
        int r = threadIdx.x & 31, s = threadIdx.x >> 5;
        int i0 = 20 * s;
        const float* ln = tin[r];
        float sum = 0.f;
        int jlo = i0 - 16; if (jlo < 0) jlo = 0;
        int jhi = i0 + 15; if (jhi > D - 1) jhi = D - 1;
        for (int j = jlo; j <= jhi; ++j) sum += ln[j];
        #pragma unroll 4
        for (int k = 0; k < 20; ++k) {
            int i = i0 + k;
            filt[i][r] = sum;
            int add = i + 16, rem = i - 16;
            if (add <= D - 1) sum += ln[add];
            if (rem >= 0)     sum -= ln[rem];
        }
    }
    __syncthreads();

    int r = threadIdx.x & 31;
    for (int c = (threadIdx.x >> 5); c < D; c += 8)
        out[(size_t)c * DD + L0 + r] = filt[c][r];
}

// plain float middle pass
__global__ __launch_bounds__(256) void box_rot_f32_kernel(
    const float* __restrict__ fin, float* __restrict__ out)
{
    __shared__ float tin[32][161];
    __shared__ float filt[160][33];
    int L0 = blockIdx.x * 32;
    size_t base = (size_t)L0 * D;

    const float4* s4 = (const float4*)(fin + base);
    for (int i = threadIdx.x; i < 32 * (D / 4); i += 256) {
        float4 v = s4[i];
        int e = i * 4, r = e / D, c = e - r * D;
        tin[r][c] = v.x; tin[r][c+1] = v.y; tin[r][c+2] = v.z; tin[r][c+3] = v.w;
    }
    __syncthreads();

    {
        int r = threadIdx.x & 31, s = threadIdx.x >> 5;
        int i0 = 20 * s;
        const float* ln = tin[r];
        float sum = 0.f;
        int jlo = i0 - 16; if (jlo < 0) jlo = 0;
        int jhi = i0 + 15; if (jhi > D - 1) jhi = D - 1;
        for (int j = jlo; j <= jhi; ++j) sum += ln[j];
        #pragma unroll 4
        for (int k = 0; k < 20; ++k) {
            int i = i0 + k;
            filt[i][r] = sum;
            int add = i + 16, rem = i - 16;
            if (add <= D - 1) sum += ln[add];
            if (rem >= 0)     sum -= ln[rem];
        }
    }
    __syncthreads();

    int r = threadIdx.x & 31;
    for (int c = (threadIdx.x >> 5); c < D; c += 8)
        out[(size_t)c * DD + L0 + r] = filt[c][r];
}

// ---------------------------------------------------------------------------
// cs pass 3 fused with finalize.
// ---------------------------------------------------------------------------
__global__ __launch_bounds__(256) void box_rot_fin_kernel(
    const float* __restrict__ fin, const unsigned* __restrict__ cwp,
    float* __restrict__ cand, unsigned short* __restrict__ idxbuf,
    int* __restrict__ partial)
{
    __shared__ float tin[32][161];
    __shared__ float filt[160][33];
    __shared__ int lh[NBINS];
    for (int i = threadIdx.x; i < NBINS; i += 256) lh[i] = 0;

    int L0 = blockIdx.x * 32;
    size_t base = (size_t)L0 * D;
    const float4* s4 = (const float4*)(fin + base);
    for (int i = threadIdx.x; i < 32 * (D / 4); i += 256) {
        float4 v = s4[i];
        int e = i * 4, r = e / D, c = e - r * D;
        tin[r][c] = v.x; tin[r][c+1] = v.y; tin[r][c+2] = v.z; tin[r][c+3] = v.w;
    }
    __syncthreads();

    {
        int r = threadIdx.x & 31, s = threadIdx.x >> 5;
        int i0 = 20 * s;
        const float* ln = tin[r];
        float sum = 0.f;
        int jlo = i0 - 16; if (jlo < 0) jlo = 0;
        int jhi = i0 + 15; if (jhi > D - 1) jhi = D - 1;
        for (int j = jlo; j <= jhi; ++j) sum += ln[j];
        #pragma unroll 4
        for (int k = 0; k < 20; ++k) {
            int i = i0 + k;
            filt[i][r] = sum;
            int add = i + 16, rem = i - 16;
            if (add <= D - 1) sum += ln[add];
            if (rem >= 0)     sum -= ln[rem];
        }
    }
    __syncthreads();

    int r = threadIdx.x & 31;
    int L = L0 + r;
    int y = L / D, z = L - (L / D) * D;
    bool byz = (y >= HALF && y < D - HALF && z >= HALF && z < D - HALF);
    int wy = min(y + 15, D - 1) - max(y - 16, 0) + 1;
    int wz = min(z + 15, D - 1) - max(z - 16, 0) + 1;
    for (int c = (threadIdx.x >> 5); c < D; c += 8) {   // c == x
        int p = c * DD + L;
        unsigned pk = cwp[p];
        unsigned cw0 = pk & 0xFFFFu;
        unsigned cw1 = pk >> 16;
        int wx = min(c + 15, D - 1) - max(c - 16, 0) + 1;
        unsigned cw2 = (unsigned)(wx * wy * wz) - cw0 - cw1;
        float v0 = (cw0 > 100u) ? 1.f : 0.f;
        float v1 = (cw1 > 100u) ? 1.f : 0.f;
        float v2 = (cw2 > 100u) ? 1.f : 0.f;
        float border = (byz && c >= HALF && c < D - HALF) ? 1.f : 0.f;
        float cd = (border * v1 + v0 + v2 >= 2.f) ? 1.f : 0.f;
        cand[p] = cd;
        float mean = (cw1 > 0u) ? filt[c][r] / fmaxf((float)cw1, 1.f) : 0.f;
        int idx = (int)rintf(cd * mean);    // round half-to-even == jnp.round
        idx = min(max(idx, 0), NBINS - 1);
        idxbuf[p] = (unsigned short)idx;
        if (idx != 0) atomicAdd(&lh[idx], 1);   // hist[0] never consumed
    }
    __syncthreads();
    int* po = partial + blockIdx.x * NBINS;
    for (int i = threadIdx.x; i < NBINS; i += 256) po[i] = lh[i];
}

// ---------------------------------------------------------------------------
// CCL: TWO exact min-propagation generations per launch (8 launches for 16
// generations). Post-mortem R1: contiguous stores did NOT cut WRITE_SIZE
// (54MB counter value is a gfx94x-formula artifact: 54MB real writes at
// ~10us/sweep would need 5.4TB/s); sweeps are short-kernel/latency-bound
// (VALUBusy 22%, Occ 50%, HBM 12%), each ~2x its traffic floor. So the
// lever is FEWER generation boundaries, not cheaper stores.
// Scheme: for each 4-voxel z-run, gen2 = 7-point min over gen1 at runs
// {self, y+-1, x+-1}; each gen1 run recomputed redundantly from gen0 via
// its own 7-point stencil -> 13 guarded int4 loads per run (self, y+-1,
// y+-2, x+-1, x+-2, 4 xy-diagonals), all L2-slab-resident. Exactness: the
// seg mask is preserved because field!=BIGV <=> seg at every generation,
// and min6's c==BIGV guard implements where(seg, ., big). z-edges via
// shfl (interior lanes); wave-edge lanes take scalar L1-hit loads, incl.
// a from-scratch gen1 at the run boundary (p-1 / p+4).
// XCD swizzle kept: each XCD owns a contiguous 20-plane x-slab.
// ---------------------------------------------------------------------------
__device__ __forceinline__ int min6(int c, int a, int b, int d, int e, int f, int g) {
    if (c == BIGV) return BIGV;
    return min(min(min(c, a), min(b, d)), min(min(e, f), g));
}

// one masked 7-point min step for a 4-voxel z-run (lm/rm are z-edges)
__device__ __forceinline__ int4 min7_run(int4 c, int lm, int rm,
                                         int4 ym, int4 yp, int4 xm, int4 xp) {
    int4 o;
    o.x = min6(c.x, lm,  c.y, ym.x, yp.x, xm.x, xp.x);
    o.y = min6(c.y, c.x, c.z, ym.y, yp.y, xm.y, xp.y);
    o.z = min6(c.z, c.y, c.w, ym.z, yp.z, xm.z, xp.z);
    o.w = min6(c.w, c.z, rm,  ym.w, yp.w, xm.w, xp.w);
    return o;
}

__device__ __forceinline__ void wave_count(int l, int lane, int* __restrict__ cnt) {
    unsigned long long remaining = __ballot(l != BIGV);
    while (remaining) {
        int leader = __ffsll((unsigned long long)remaining) - 1;
        int ll = __shfl(l, leader, 64);
        unsigned long long mm = __ballot(l == ll);
        if (lane == leader) atomicAdd(&cnt[ll], (int)__popcll(mm & remaining));
        remaining &= ~mm;
    }
}

__device__ __forceinline__ int4 cls4(float4 v, int p0) {
    int4 l;
    l.x = (rintf(v.x) == 1.f) ? (p0 + 1) : BIGV;
    l.y = (rintf(v.y) == 1.f) ? (p0 + 2) : BIGV;
    l.z = (rintf(v.z) == 1.f) ? (p0 + 3) : BIGV;
    l.w = (rintf(v.w) == 1.f) ? (p0 + 4) : BIGV;
    return l;
}

struct LabLd {
    const int* __restrict__ a;
    __device__ __forceinline__ int4 v(int p) const { return ((const int4*)a)[p >> 2]; }
    __device__ __forceinline__ int  s(int p) const { return a[p]; }
};
struct DataLd {
    const float* __restrict__ a;
    __device__ __forceinline__ int4 v(int p) const { return cls4(((const float4*)a)[p >> 2], p); }
    __device__ __forceinline__ int  s(int p) const { return (rintf(a[p]) == 1.f) ? (p + 1) : BIGV; }
};

template<typename LD>
__device__ __forceinline__ int4 fused2_chunk(LD ld, int p, int lane)
{
    const int4 BIG4 = make_int4(BIGV, BIGV, BIGV, BIGV);
    int z0 = p % D;
    int rr = p / D;
    int yy = rr % D;
    int xx = rr / D;
    bool gyp = yy < D - 1, gym = yy > 0, gxp = xx < D - 1, gxm = xx > 0;

    int4 C  = ld.v(p);
    int4 Yp = gyp ? ld.v(p + D)  : BIG4;
    int4 Ym = gym ? ld.v(p - D)  : BIG4;
    int4 Xp = gxp ? ld.v(p + DD) : BIG4;
    int4 Xm = gxm ? ld.v(p - DD) : BIG4;

    // z-edges of the 5 gen0 run-sets: shfl for interior lanes, scalar loads
    // at wave edges, BIGV at row boundaries. (A run never crosses a row:
    // D%4==0. Interior shfl partners share rr, so guards match.)
    bool lz = (z0 == 0), rz = (z0 == D - 4);
    bool l0  = (lane == 0)  && !lz;
    bool l63 = (lane == 63) && !rz;
    int lmC  = __shfl_up(C.w, 1),  rmC  = __shfl_down(C.x, 1);
    int lmYp = __shfl_up(Yp.w, 1), rmYp = __shfl_down(Yp.x, 1);
    int lmYm = __shfl_up(Ym.w, 1), rmYm = __shfl_down(Ym.x, 1);
    int lmXp = __shfl_up(Xp.w, 1), rmXp = __shfl_down(Xp.x, 1);
    int lmXm = __shfl_up(Xm.w, 1), rmXm = __shfl_down(Xm.x, 1);
    if (lz) { lmC = lmYp = lmYm = lmXp = lmXm = BIGV; }
    if (rz) { rmC = rmYp = rmYm = rmXp = rmXm = BIGV; }
    if (l0) {
        lmC  = ld.s(p - 1);
        lmYp = gyp ? ld.s(p + D - 1)  : BIGV;
        lmYm = gym ? ld.s(p - D - 1)  : BIGV;
        lmXp = gxp ? ld.s(p + DD - 1) : BIGV;
        lmXm = gxm ? ld.s(p - DD - 1) : BIGV;
    }
    if (l63) {
        rmC  = ld.s(p + 4);
        rmYp = gyp ? ld.s(p + D + 4)  : BIGV;
        rmYm = gym ? ld.s(p - D + 4)  : BIGV;
        rmXp = gxp ? ld.s(p + DD + 4) : BIGV;
        rmXm = gxm ? ld.s(p - DD + 4) : BIGV;
    }

    // gen1 at the 5 runs (neighbor-arg order irrelevant: min is commutative;
    // only c carries the seg mask)
    int4 g1C = min7_run(C, lmC, rmC, Ym, Yp, Xm, Xp);

    int4 Yp2 = (yy < D - 2)  ? ld.v(p + 2 * D)  : BIG4;
    int4 Dpp = (gxp && gyp)  ? ld.v(p + DD + D) : BIG4;
    int4 Dmp = (gxm && gyp)  ? ld.v(p - DD + D) : BIG4;
    int4 g1Yp = min7_run(Yp, lmYp, rmYp, C, Yp2, Dmp, Dpp);

    int4 Ym2 = (yy > 1)      ? ld.v(p - 2 * D)  : BIG4;
    int4 Dpm = (gxp && gym)  ? ld.v(p + DD - D) : BIG4;
    int4 Dmm = (gxm && gym)  ? ld.v(p - DD - D) : BIG4;
    int4 g1Ym = min7_run(Ym, lmYm, rmYm, Ym2, C, Dmm, Dpm);

    int4 Xp2 = (xx < D - 2)  ? ld.v(p + 2 * DD) : BIG4;
    int4 g1Xp = min7_run(Xp, lmXp, rmXp, Dpm, Dpp, C, Xp2);

    int4 Xm2 = (xx > 1)      ? ld.v(p - 2 * DD) : BIG4;
    int4 g1Xm = min7_run(Xm, lmXm, rmXm, Dmm, Dmp, Xm2, C);

    // gen1 z-edges of the self run: shfl interior; wave-edge lanes compute
    // gen1(p-1)/(p+4) from scratch (reusing the gen0 edge scalars, which sit
    // at (p-1)+-D/+-DD and (p+4)+-D/+-DD respectively; same row => same guards).
    int lmG = __shfl_up(g1C.w, 1), rmG = __shfl_down(g1C.x, 1);
    if (lz) lmG = BIGV;
    if (rz) rmG = BIGV;
    if (l0) {
        // z0 >= 4 here, so p-2 stays in-row
        lmG = min6(lmC, ld.s(p - 2), C.x, lmYp, lmYm, lmXp, lmXm);
    }
    if (l63) {
        // z0 <= D-8 here, so p+5 stays in-row
        rmG = min6(rmC, C.w, ld.s(p + 5), rmYp, rmYm, rmXp, rmXm);
    }

    return min7_run(g1C, lmG, rmG, g1Ym, g1Yp, g1Xm, g1Xp);
}

// gens 1+2 straight from data (gen0 derived, never stored)
__global__ __launch_bounds__(512) void ccl_fused2_data_kernel(
    const float* __restrict__ data, int* __restrict__ outp)
{
    int b = blockIdx.x;
    int sb = (b & 7) * (SGRID / 8) + (b >> 3);   // XCD-contiguous x-slab
    int lane = threadIdx.x & 63;
    int wv   = threadIdx.x >> 6;
    int wbase = sb * 4096 + wv * 512;
    int pA = wbase + 4 * lane;
    int pB = pA + 256;

    DataLd ld{data};
    int4 oA = fused2_chunk(ld, pA, lane);
    int4 oB = fused2_chunk(ld, pB, lane);

    int4* out4 = (int4*)outp;
    out4[pA >> 2] = oA; out4[pB >> 2] = oB;
}

template<int COUNT>
__global__ __launch_bounds__(512) void ccl_fused2_kernel(
    const int* __restrict__ lab, int* __restrict__ outp, int* __restrict__ cnt)
{
    int b = blockIdx.x;
    int sb = (b & 7) * (SGRID / 8) + (b >> 3);   // XCD-contiguous x-slab
    int lane = threadIdx.x & 63;
    int wv   = threadIdx.x >> 6;
    int wbase = sb * 4096 + wv * 512;
    int pA = wbase + 4 * lane;
    int pB = pA + 256;

    LabLd ld{lab};
    int4 oA = fused2_chunk(ld, pA, lane);
    int4 oB = fused2_chunk(ld, pB, lane);

    int4* out4 = (int4*)outp;
    out4[pA >> 2] = oA; out4[pB >> 2] = oB;

    if (COUNT) {   // final generation: component-size count from registers
        wave_count(oA.x, lane, cnt);
        wave_count(oA.y, lane, cnt);
        wave_count(oA.z, lane, cnt);
        wave_count(oA.w, lane, cnt);
        wave_count(oB.x, lane, cnt);
        wave_count(oB.y, lane, cnt);
        wave_count(oB.z, lane, cnt);
        wave_count(oB.w, lane, cnt);
    }
}

// ---------------------------------------------------------------------------
// hist[bin] = sum over RGRID block partials (coalesced, L2-resident)
// ---------------------------------------------------------------------------
__global__ __launch_bounds__(256) void hist_reduce_kernel(
    const int* __restrict__ partial, int* __restrict__ hist)
{
    int bin = blockIdx.x * 256 + threadIdx.x;   // 16 x 256 = 4096
    int s = 0;
    #pragma unroll 4
    for (int b = 0; b < RGRID; ++b) s += partial[b * NBINS + bin];
    hist[bin] = s;
}

// ---------------------------------------------------------------------------
// histogram post-processing: rec -> ph_full (normalized), S = sum hist*ph.
// ---------------------------------------------------------------------------
__global__ __launch_bounds__(256) void hist_post_kernel(
    const int* __restrict__ hist, float* __restrict__ ph_full,
    float* __restrict__ Sout)
{
    __shared__ float red[256];
    int t = threadIdx.x;

    float loc = 0.f;
    for (int b = t; b < NBINS; b += 256)
        if (b >= 1) loc += (float)hist[b];
    red[t] = loc; __syncthreads();
    for (int o = 128; o > 0; o >>= 1) { if (t < o) red[t] += red[t + o]; __syncthreads(); }
    float numb = red[0]; __syncthreads();

    loc = 0.f;
    for (int b = t; b < NBINS; b += 256) {
        float r = 0.f;
        if (b >= 1) {
            int h = hist[b];
            if (h > 0) r = numb / (float)h;
        }
        ph_full[b] = r;
        loc += r;
    }
    red[t] = loc; __syncthreads();
    for (int o = 128; o > 0; o >>= 1) { if (t < o) red[t] += red[t + o]; __syncthreads(); }
    float sumrec = red[0]; __syncthreads();
    float inv_sumrec = (sumrec > 0.f) ? 1.f / sumrec : 0.f;

    loc = 0.f;
    for (int b = t; b < NBINS; b += 256) {
        float ph = (b >= 1) ? ph_full[b] * inv_sumrec : 0.f;
        ph_full[b] = ph;
        loc += ph * (float)hist[b];
    }
    red[t] = loc; __syncthreads();
    for (int o = 128; o > 0; o >>= 1) { if (t < o) red[t] += red[t + o]; __syncthreads(); }
    if (t == 0) Sout[0] = (red[0] > 0.f) ? red[0] : 1.f;
}

__global__ __launch_bounds__(256) void proba_kernel(
    const unsigned short* __restrict__ idxbuf,
    const float* __restrict__ ph_full, const float* __restrict__ Sv,
    float* __restrict__ outp)
{
    int t = blockIdx.x * blockDim.x + threadIdx.x;   // exact grid NVOX/4
    ushort4 i4 = ((const ushort4*)idxbuf)[t];
    float inv = 1.f / Sv[0];
    float4 o;
    o.x = ph_full[i4.x] * inv;
    o.y = ph_full[i4.y] * inv;
    o.z = ph_full[i4.z] * inv;
    o.w = ph_full[i4.w] * inv;
    ((float4*)outp)[t] = o;
}

// ---------------------------------------------------------------------------
extern "C" void kernel_launch(void* const* d_in, const int* in_sizes, int n_in,
                              void* d_out, int out_size, void* d_ws, size_t ws_size,
                              hipStream_t stream)
{
    const float* data = (const float*)d_in[0];
    float* out   = (float*)d_out;
    float* cand  = out;
    float* proba = out + NVOX;

    char* ws = (char*)d_ws;
    const size_t NB = (size_t)NVOX * sizeof(float);
    float* W1 = (float*)(ws);
    float* W2 = (float*)(ws + NB);
    float* W3 = (float*)(ws + 2 * NB);
    int*   cnt  = (int*)(ws + 3 * NB);                 // NVOX+1 ints
    float* ph   = (float*)(ws + 4 * NB + 16);
    int*   hist = (int*)  (ws + 4 * NB + 16 + NBINS * 4);
    float* Sv   = (float*)(ws + 4 * NB + 16 + 2 * NBINS * 4);
    unsigned short* idxbuf = (unsigned short*)cnt;     // cnt dead after cs pass 1
    int* partial = (int*)W2;                           // W2 dead after cs pass 2

    dim3 rb(256), rg(RGRID);               // 800 blocks (rotate passes)
    dim3 sbk(512), sg(SGRID);              // 1000 blocks (fused sweeps)
    dim3 pb(256), pg(NVOX / 4 / 256);      // 4000 blocks (proba x4)

    hipMemsetAsync(cnt, 0, (NVOX + 1) * sizeof(int), stream);

    // cw packed box sums via rotate pipeline
    box_rot_int_kernel<0><<<rg, rb, 0, stream>>>(data, (unsigned*)W1);
    box_rot_int_kernel<1><<<rg, rb, 0, stream>>>(W1, (unsigned*)W3);
    box_rot_int_kernel<1><<<rg, rb, 0, stream>>>(W3, (unsigned*)W1);
    unsigned* cwp = (unsigned*)W1;         // original layout

    // CCL: 16 exact generations in 8 launches (2 gens each). data->gen2 in
    // W2; ping-pong; final launch (gen15+16) fuses the component-size count.
    ccl_fused2_data_kernel<<<sg, sbk, 0, stream>>>(data, (int*)W2);       // g2
    ccl_fused2_kernel<0><<<sg, sbk, 0, stream>>>((int*)W2, (int*)W3, nullptr); // g4
    ccl_fused2_kernel<0><<<sg, sbk, 0, stream>>>((int*)W3, (int*)W2, nullptr); // g6
    ccl_fused2_kernel<0><<<sg, sbk, 0, stream>>>((int*)W2, (int*)W3, nullptr); // g8
    ccl_fused2_kernel<0><<<sg, sbk, 0, stream>>>((int*)W3, (int*)W2, nullptr); // g10
    ccl_fused2_kernel<0><<<sg, sbk, 0, stream>>>((int*)W2, (int*)W3, nullptr); // g12
    ccl_fused2_kernel<0><<<sg, sbk, 0, stream>>>((int*)W3, (int*)W2, nullptr); // g14
    ccl_fused2_kernel<1><<<sg, sbk, 0, stream>>>((int*)W2, (int*)W3, cnt);     // g16
    int* lab = (int*)W3;                   // gen-16 labels

    // cs float box sums
    box_rot_f32_g_kernel<<<rg, rb, 0, stream>>>(lab, cnt, cwp, W2);
    box_rot_f32_kernel<<<rg, rb, 0, stream>>>(W2, W3);
    box_rot_fin_kernel<<<rg, rb, 0, stream>>>(W3, cwp, cand, idxbuf, partial);

    hist_reduce_kernel<<<dim3(16), dim3(256), 0, stream>>>(partial, hist);
    hist_post_kernel<<<1, 256, 0, stream>>>(hist, ph, Sv);
    proba_kernel<<<pg, pb, 0, stream>>>(idxbuf, ph, Sv, proba);
}

// Round 3
// 390.972 us; speedup vs baseline: 1.2347x; 1.2347x over previous
//
#include <hip/hip_runtime.h>
#include <cmath>

#define D 160
#define DD (D*D)          // 25600
#define NVOX (D*D*D)
#define BIGV (NVOX + 2)
#define NBINS 4096
#define HALF 16
#define RGRID 800         // rotate-pass blocks = DD/32, also hist partial count
#define SGRID 1000        // sweep blocks (512 thr, 8 cells/thread)
#define ZGRID 1000        // zero-cnt blocks fused into sweep 4

// ---------------------------------------------------------------------------
// Rotate box pass as a device block-function (512-thread mapping: 16 strips
// x 10 elems), so it can ride inside sweep launches as extra blocks.
// MODE 0: pack classes from raw float data. MODE 1: pass-through uint.
// Layout (a,b,c) c-contig -> filter along c -> write (c,a,b).
// ---------------------------------------------------------------------------
template<int MODE>
__device__ __forceinline__ void rot_block(
    const void* __restrict__ vin, unsigned* __restrict__ out, int bi, int tid)
{
    __shared__ unsigned tin[32][161];
    __shared__ unsigned filt[160][33];
    int L0 = bi * 32;
    size_t base = (size_t)L0 * D;

    if (MODE == 0) {
        const float4* s4 = (const float4*)((const float*)vin + base);
        for (int i = tid; i < 32 * (D / 4); i += 512) {
            float4 v = s4[i];
            int e = i * 4, r = e / D, c = e - r * D;
            float rr;
            rr = rintf(v.x); tin[r][c]   = (rr==0.f) | ((rr==1.f)?0x10000u:0u);
            rr = rintf(v.y); tin[r][c+1] = (rr==0.f) | ((rr==1.f)?0x10000u:0u);
            rr = rintf(v.z); tin[r][c+2] = (rr==0.f) | ((rr==1.f)?0x10000u:0u);
            rr = rintf(v.w); tin[r][c+3] = (rr==0.f) | ((rr==1.f)?0x10000u:0u);
        }
    } else {
        const uint4* s4 = (const uint4*)((const unsigned*)vin + base);
        for (int i = tid; i < 32 * (D / 4); i += 512) {
            uint4 v = s4[i];
            int e = i * 4, r = e / D, c = e - r * D;
            tin[r][c] = v.x; tin[r][c+1] = v.y; tin[r][c+2] = v.z; tin[r][c+3] = v.w;
        }
    }
    __syncthreads();

    {
        int r = tid & 31, s = tid >> 5;      // s in [0,16)
        int i0 = 10 * s;
        const unsigned* ln = tin[r];
        unsigned sum = 0u;
        int jlo = i0 - 16; if (jlo < 0) jlo = 0;
        int jhi = i0 + 15; if (jhi > D - 1) jhi = D - 1;
        for (int j = jlo; j <= jhi; ++j) sum += ln[j];
        #pragma unroll
        for (int k = 0; k < 10; ++k) {
            int i = i0 + k;
            filt[i][r] = sum;
            int add = i + 16, rem = i - 16;
            if (add <= D - 1) sum += ln[add];
            if (rem >= 0)     sum -= ln[rem];
        }
    }
    __syncthreads();

    int r = tid & 31;
    for (int c = (tid >> 5); c < D; c += 16)
        out[(size_t)c * DD + L0 + r] = filt[c][r];
}

// ---------------------------------------------------------------------------
// Rotate box filter, FLOAT path, pass 1: fuses the lsize*valid gather.
// ---------------------------------------------------------------------------
__global__ __launch_bounds__(256) void box_rot_f32_g_kernel(
    const int* __restrict__ lab, const int* __restrict__ cnt,
    const unsigned* __restrict__ cwp, float* __restrict__ out)
{
    __shared__ float tin[32][161];
    __shared__ float filt[160][33];
    int L0 = blockIdx.x * 32;
    size_t base = (size_t)L0 * D;

    const int4*  lab4 = (const int4*)(lab + base);
    const uint4* cw4  = (const uint4*)(cwp + base);
    for (int i = threadIdx.x; i < 32 * (D / 4); i += 256) {
        int4 l = lab4[i];
        uint4 cw = cw4[i];
        int e = i * 4, r = e / D, c = e - r * D;
        tin[r][c]   = (l.x != BIGV && (cw.x >> 16) > 100u) ? (float)cnt[l.x] : 0.f;
        tin[r][c+1] = (l.y != BIGV && (cw.y >> 16) > 100u) ? (float)cnt[l.y] : 0.f;
        tin[r][c+2] = (l.z != BIGV && (cw.z >> 16) > 100u) ? (float)cnt[l.z] : 0.f;
        tin[r][c+3] = (l.w != BIGV && (cw.w >> 16) > 100u) ? (float)cnt[l.w] : 0.f;
    }
    __syncthreads();

    {
        int r = threadIdx.x & 31, s = threadIdx.x >> 5;
        int i0 = 20 * s;
        const float* ln = tin[r];
        float sum = 0.f;
        int jlo = i0 - 16; if (jlo < 0) jlo = 0;
        int jhi = i0 + 15; if (jhi > D - 1) jhi = D - 1;
        for (int j = jlo; j <= jhi; ++j) sum += ln[j];
        #pragma unroll 4
        for (int k = 0; k < 20; ++k) {
            int i = i0 + k;
            filt[i][r] = sum;
            int add = i + 16, rem = i - 16;
            if (add <= D - 1) sum += ln[add];
            if (rem >= 0)     sum -= ln[rem];
        }
    }
    __syncthreads();

    int r = threadIdx.x & 31;
    for (int c = (threadIdx.x >> 5); c < D; c += 8)
        out[(size_t)c * DD + L0 + r] = filt[c][r];
}

// plain float middle pass
__global__ __launch_bounds__(256) void box_rot_f32_kernel(
    const float* __restrict__ fin, float* __restrict__ out)
{
    __shared__ float tin[32][161];
    __shared__ float filt[160][33];
    int L0 = blockIdx.x * 32;
    size_t base = (size_t)L0 * D;

    const float4* s4 = (const float4*)(fin + base);
    for (int i = threadIdx.x; i < 32 * (D / 4); i += 256) {
        float4 v = s4[i];
        int e = i * 4, r = e / D, c = e - r * D;
        tin[r][c] = v.x; tin[r][c+1] = v.y; tin[r][c+2] = v.z; tin[r][c+3] = v.w;
    }
    __syncthreads();

    {
        int r = threadIdx.x & 31, s = threadIdx.x >> 5;
        int i0 = 20 * s;
        const float* ln = tin[r];
        float sum = 0.f;
        int jlo = i0 - 16; if (jlo < 0) jlo = 0;
        int jhi = i0 + 15; if (jhi > D - 1) jhi = D - 1;
        for (int j = jlo; j <= jhi; ++j) sum += ln[j];
        #pragma unroll 4
        for (int k = 0; k < 20; ++k) {
            int i = i0 + k;
            filt[i][r] = sum;
            int add = i + 16, rem = i - 16;
            if (add <= D - 1) sum += ln[add];
            if (rem >= 0)     sum -= ln[rem];
        }
    }
    __syncthreads();

    int r = threadIdx.x & 31;
    for (int c = (threadIdx.x >> 5); c < D; c += 8)
        out[(size_t)c * DD + L0 + r] = filt[c][r];
}

// ---------------------------------------------------------------------------
// cs pass 3 fused with finalize: cand + idx + LDS histogram.
// ---------------------------------------------------------------------------
__global__ __launch_bounds__(256) void box_rot_fin_kernel(
    const float* __restrict__ fin, const unsigned* __restrict__ cwp,
    float* __restrict__ cand, unsigned short* __restrict__ idxbuf,
    int* __restrict__ partial)
{
    __shared__ float tin[32][161];
    __shared__ float filt[160][33];
    __shared__ int lh[NBINS];
    for (int i = threadIdx.x; i < NBINS; i += 256) lh[i] = 0;

    int L0 = blockIdx.x * 32;
    size_t base = (size_t)L0 * D;
    const float4* s4 = (const float4*)(fin + base);
    for (int i = threadIdx.x; i < 32 * (D / 4); i += 256) {
        float4 v = s4[i];
        int e = i * 4, r = e / D, c = e - r * D;
        tin[r][c] = v.x; tin[r][c+1] = v.y; tin[r][c+2] = v.z; tin[r][c+3] = v.w;
    }
    __syncthreads();

    {
        int r = threadIdx.x & 31, s = threadIdx.x >> 5;
        int i0 = 20 * s;
        const float* ln = tin[r];
        float sum = 0.f;
        int jlo = i0 - 16; if (jlo < 0) jlo = 0;
        int jhi = i0 + 15; if (jhi > D - 1) jhi = D - 1;
        for (int j = jlo; j <= jhi; ++j) sum += ln[j];
        #pragma unroll 4
        for (int k = 0; k < 20; ++k) {
            int i = i0 + k;
            filt[i][r] = sum;
            int add = i + 16, rem = i - 16;
            if (add <= D - 1) sum += ln[add];
            if (rem >= 0)     sum -= ln[rem];
        }
    }
    __syncthreads();

    int r = threadIdx.x & 31;
    int L = L0 + r;
    int y = L / D, z = L - (L / D) * D;
    bool byz = (y >= HALF && y < D - HALF && z >= HALF && z < D - HALF);
    int wy = min(y + 15, D - 1) - max(y - 16, 0) + 1;
    int wz = min(z + 15, D - 1) - max(z - 16, 0) + 1;
    for (int c = (threadIdx.x >> 5); c < D; c += 8) {   // c == x
        int p = c * DD + L;
        unsigned pk = cwp[p];
        unsigned cw0 = pk & 0xFFFFu;
        unsigned cw1 = pk >> 16;
        int wx = min(c + 15, D - 1) - max(c - 16, 0) + 1;
        unsigned cw2 = (unsigned)(wx * wy * wz) - cw0 - cw1;
        float v0 = (cw0 > 100u) ? 1.f : 0.f;
        float v1 = (cw1 > 100u) ? 1.f : 0.f;
        float v2 = (cw2 > 100u) ? 1.f : 0.f;
        float border = (byz && c >= HALF && c < D - HALF) ? 1.f : 0.f;
        float cd = (border * v1 + v0 + v2 >= 2.f) ? 1.f : 0.f;
        cand[p] = cd;
        float mean = (cw1 > 0u) ? filt[c][r] / fmaxf((float)cw1, 1.f) : 0.f;
        int idx = (int)rintf(cd * mean);    // round half-to-even == jnp.round
        idx = min(max(idx, 0), NBINS - 1);
        idxbuf[p] = (unsigned short)idx;
        if (idx != 0) atomicAdd(&lh[idx], 1);   // hist[0] never consumed
    }
    __syncthreads();
    int* po = partial + blockIdx.x * NBINS;
    for (int i = threadIdx.x; i < NBINS; i += 256) po[i] = lh[i];
}

// ---------------------------------------------------------------------------
// CCL: 16 single-generation sweeps (R2 post-mortem: 2-gen register fusion
// costs 2.8x a sweep — redundancy 5x loses; 16 launches is the structure).
// R1 contiguous half-wave chunk layout. During sweeps 1-4 the machine is
// mostly idle (VALU 22%, HBM 12%) -> fuse the data-independent cw rotate
// passes (1-3) and the cnt zeroing (4) into those launches as extra blocks.
// Sweep ping-pong borrows the cnt region (W4) as third buffer for g2/g3 so
// it never collides with the rotate buffers (W1/W3).
// XCD swizzle: each XCD owns a contiguous 20-plane x-slab.
// ---------------------------------------------------------------------------
__device__ __forceinline__ int min6(int c, int a, int b, int d, int e, int f, int g) {
    if (c == BIGV) return BIGV;
    return min(min(min(c, a), min(b, d)), min(min(e, f), g));
}

__device__ __forceinline__ int4 min7_run(int4 c, int lm, int rm,
                                         int4 ym, int4 yp, int4 xm, int4 xp) {
    int4 o;
    o.x = min6(c.x, lm,  c.y, ym.x, yp.x, xm.x, xp.x);
    o.y = min6(c.y, c.x, c.z, ym.y, yp.y, xm.y, xp.y);
    o.z = min6(c.z, c.y, c.w, ym.z, yp.z, xm.z, xp.z);
    o.w = min6(c.w, c.z, rm,  ym.w, yp.w, xm.w, xp.w);
    return o;
}

__device__ __forceinline__ void wave_count(int l, int lane, int* __restrict__ cnt) {
    unsigned long long remaining = __ballot(l != BIGV);
    while (remaining) {
        int leader = __ffsll((unsigned long long)remaining) - 1;
        int ll = __shfl(l, leader, 64);
        unsigned long long mm = __ballot(l == ll);
        if (lane == leader) atomicAdd(&cnt[ll], (int)__popcll(mm & remaining));
        remaining &= ~mm;
    }
}

__device__ __forceinline__ int4 cls4(float4 v, int p0) {
    int4 l;
    l.x = (rintf(v.x) == 1.f) ? (p0 + 1) : BIGV;
    l.y = (rintf(v.y) == 1.f) ? (p0 + 2) : BIGV;
    l.z = (rintf(v.z) == 1.f) ? (p0 + 3) : BIGV;
    l.w = (rintf(v.w) == 1.f) ? (p0 + 4) : BIGV;
    return l;
}

struct LabLd {
    const int* __restrict__ a;
    __device__ __forceinline__ int4 v(int p) const { return ((const int4*)a)[p >> 2]; }
    __device__ __forceinline__ int  s(int p) const { return a[p]; }
};
struct DataLd {
    const float* __restrict__ a;
    __device__ __forceinline__ int4 v(int p) const { return cls4(((const float4*)a)[p >> 2], p); }
    __device__ __forceinline__ int  s(int p) const { return (rintf(a[p]) == 1.f) ? (p + 1) : BIGV; }
};

template<typename LDT, int COUNT>
__device__ __forceinline__ void sweep_block(
    LDT ld, int* __restrict__ outp, int* __restrict__ cnt, int b, int tid)
{
    const int4 BIG4 = make_int4(BIGV, BIGV, BIGV, BIGV);
    int sb = (b & 7) * (SGRID / 8) + (b >> 3);   // XCD-contiguous x-slab
    int lane = tid & 63;
    int wv   = tid >> 6;
    int wbase = sb * 4096 + wv * 512;
    int pA = wbase + 4 * lane;
    int pB = pA + 256;

    int4 cA = ld.v(pA), cB = ld.v(pB);

    int zA = pA % D, zB = pB % D;
    int lmA = __shfl_up(cA.w, 1);
    int rmA = __shfl_down(cA.x, 1);
    int lmB = __shfl_up(cB.w, 1);
    int rmB = __shfl_down(cB.x, 1);
    int stA = __shfl(cB.x, 0, 64);   // voxel wbase+256 (A.lane63 right nbr)
    int stB = __shfl(cA.w, 63, 64);  // voxel wbase+255 (B.lane0 left nbr)
    if (lane == 63) rmA = stA;
    if (lane == 0)  lmB = stB;
    if (zA == 0)          lmA = BIGV;
    else if (lane == 0)   lmA = ld.s(pA - 1);
    if (zA == D - 4)      rmA = BIGV;
    if (zB == 0)          lmB = BIGV;
    if (zB == D - 4)      rmB = BIGV;
    else if (lane == 63)  rmB = ld.s(pB + 4);

    int rA = pA / D, yA = rA % D, xA = rA / D;
    int4 ylA = (yA > 0)     ? ld.v(pA - D)  : BIG4;
    int4 yhA = (yA < D - 1) ? ld.v(pA + D)  : BIG4;
    int4 xlA = (xA > 0)     ? ld.v(pA - DD) : BIG4;
    int4 xhA = (xA < D - 1) ? ld.v(pA + DD) : BIG4;
    int4 oA = min7_run(cA, lmA, rmA, ylA, yhA, xlA, xhA);

    int rB = pB / D, yB = rB % D, xB = rB / D;
    int4 ylB = (yB > 0)     ? ld.v(pB - D)  : BIG4;
    int4 yhB = (yB < D - 1) ? ld.v(pB + D)  : BIG4;
    int4 xlB = (xB > 0)     ? ld.v(pB - DD) : BIG4;
    int4 xhB = (xB < D - 1) ? ld.v(pB + DD) : BIG4;
    int4 oB = min7_run(cB, lmB, rmB, ylB, yhB, xlB, xhB);

    int4* out4 = (int4*)outp;
    out4[pA >> 2] = oA; out4[pB >> 2] = oB;

    if (COUNT) {   // final generation: component-size count from registers
        wave_count(oA.x, lane, cnt);
        wave_count(oA.y, lane, cnt);
        wave_count(oA.z, lane, cnt);
        wave_count(oA.w, lane, cnt);
        wave_count(oB.x, lane, cnt);
        wave_count(oB.y, lane, cnt);
        wave_count(oB.z, lane, cnt);
        wave_count(oB.w, lane, cnt);
    }
}

// plain sweeps (g5..g15)
__global__ __launch_bounds__(512) void ccl_sweep_kernel(
    const int* __restrict__ lab, int* __restrict__ outp)
{
    LabLd ld{lab};
    sweep_block<LabLd, 0>(ld, outp, nullptr, blockIdx.x, threadIdx.x);
}

// final sweep (g16) + component-size count
__global__ __launch_bounds__(512) void ccl_sweep_count_kernel(
    const int* __restrict__ lab, int* __restrict__ outp, int* __restrict__ cnt)
{
    LabLd ld{lab};
    sweep_block<LabLd, 1>(ld, outp, cnt, blockIdx.x, threadIdx.x);
}

// sweep + rotate pass fused (g1..g3). MODE0: sweep from data + rot pass1
// (pack classes from data). MODE1: sweep from labels + rot pass-through.
template<int MODE>
__global__ __launch_bounds__(512) void sweep_rot_kernel(
    const float* __restrict__ data, const int* __restrict__ labsrc,
    int* __restrict__ swdst,
    const void* __restrict__ rin, unsigned* __restrict__ rout)
{
    if ((int)blockIdx.x < SGRID) {
        if (MODE == 0) {
            DataLd ld{data};
            sweep_block<DataLd, 0>(ld, swdst, nullptr, blockIdx.x, threadIdx.x);
        } else {
            LabLd ld{labsrc};
            sweep_block<LabLd, 0>(ld, swdst, nullptr, blockIdx.x, threadIdx.x);
        }
    } else {
        rot_block<MODE>(rin, rout, blockIdx.x - SGRID, threadIdx.x);
    }
}

// sweep g4 + zero the cnt region (W4 dead after g3 read it; must be zero
// before g16's atomics). Replaces the upfront hipMemsetAsync.
__global__ __launch_bounds__(512) void sweep_zero_kernel(
    const int* __restrict__ labsrc, int* __restrict__ swdst,
    int* __restrict__ zbuf)
{
    if ((int)blockIdx.x < SGRID) {
        LabLd ld{labsrc};
        sweep_block<LabLd, 0>(ld, swdst, nullptr, blockIdx.x, threadIdx.x);
    } else {
        int zb = blockIdx.x - SGRID;                 // 0..ZGRID-1
        int t = (zb * 512 + threadIdx.x) * 2;        // int4 units
        const int4 z4 = make_int4(0, 0, 0, 0);
        ((int4*)zbuf)[t] = z4; ((int4*)zbuf)[t + 1] = z4;   // 1000*512*8 = NVOX ints
        if (zb == 0 && threadIdx.x == 0) zbuf[NVOX] = 0;    // cnt[NVOX]
    }
}

// ---------------------------------------------------------------------------
// hist[bin] = sum over RGRID block partials (coalesced, L2-resident)
// ---------------------------------------------------------------------------
__global__ __launch_bounds__(256) void hist_reduce_kernel(
    const int* __restrict__ partial, int* __restrict__ hist)
{
    int bin = blockIdx.x * 256 + threadIdx.x;   // 16 x 256 = 4096
    int s = 0;
    #pragma unroll 4
    for (int b = 0; b < RGRID; ++b) s += partial[b * NBINS + bin];
    hist[bin] = s;
}

// ---------------------------------------------------------------------------
// histogram post-processing: rec -> ph_full (normalized), S = sum hist*ph.
// ---------------------------------------------------------------------------
__global__ __launch_bounds__(256) void hist_post_kernel(
    const int* __restrict__ hist, float* __restrict__ ph_full,
    float* __restrict__ Sout)
{
    __shared__ float red[256];
    int t = threadIdx.x;

    float loc = 0.f;
    for (int b = t; b < NBINS; b += 256)
        if (b >= 1) loc += (float)hist[b];
    red[t] = loc; __syncthreads();
    for (int o = 128; o > 0; o >>= 1) { if (t < o) red[t] += red[t + o]; __syncthreads(); }
    float numb = red[0]; __syncthreads();

    loc = 0.f;
    for (int b = t; b < NBINS; b += 256) {
        float r = 0.f;
        if (b >= 1) {
            int h = hist[b];
            if (h > 0) r = numb / (float)h;
        }
        ph_full[b] = r;
        loc += r;
    }
    red[t] = loc; __syncthreads();
    for (int o = 128; o > 0; o >>= 1) { if (t < o) red[t] += red[t + o]; __syncthreads(); }
    float sumrec = red[0]; __syncthreads();
    float inv_sumrec = (sumrec > 0.f) ? 1.f / sumrec : 0.f;

    loc = 0.f;
    for (int b = t; b < NBINS; b += 256) {
        float ph = (b >= 1) ? ph_full[b] * inv_sumrec : 0.f;
        ph_full[b] = ph;
        loc += ph * (float)hist[b];
    }
    red[t] = loc; __syncthreads();
    for (int o = 128; o > 0; o >>= 1) { if (t < o) red[t] += red[t + o]; __syncthreads(); }
    if (t == 0) Sout[0] = (red[0] > 0.f) ? red[0] : 1.f;
}

__global__ __launch_bounds__(256) void proba_kernel(
    const unsigned short* __restrict__ idxbuf,
    const float* __restrict__ ph_full, const float* __restrict__ Sv,
    float* __restrict__ outp)
{
    int t = blockIdx.x * blockDim.x + threadIdx.x;   // exact grid NVOX/4
    ushort4 i4 = ((const ushort4*)idxbuf)[t];
    float inv = 1.f / Sv[0];
    float4 o;
    o.x = ph_full[i4.x] * inv;
    o.y = ph_full[i4.y] * inv;
    o.z = ph_full[i4.z] * inv;
    o.w = ph_full[i4.w] * inv;
    ((float4*)outp)[t] = o;
}

// ---------------------------------------------------------------------------
extern "C" void kernel_launch(void* const* d_in, const int* in_sizes, int n_in,
                              void* d_out, int out_size, void* d_ws, size_t ws_size,
                              hipStream_t stream)
{
    const float* data = (const float*)d_in[0];
    float* out   = (float*)d_out;
    float* cand  = out;
    float* proba = out + NVOX;

    char* ws = (char*)d_ws;
    const size_t NB = (size_t)NVOX * sizeof(float);
    float* W1 = (float*)(ws);
    float* W2 = (float*)(ws + NB);
    float* W3 = (float*)(ws + 2 * NB);
    int*   W4 = (int*)(ws + 3 * NB);                   // cnt region / 3rd ping-pong buf
    int*   cnt  = W4;                                  // NVOX+1 ints (last int in pad)
    float* ph   = (float*)(ws + 4 * NB + 16);
    int*   hist = (int*)  (ws + 4 * NB + 16 + NBINS * 4);
    float* Sv   = (float*)(ws + 4 * NB + 16 + 2 * NBINS * 4);
    unsigned short* idxbuf = (unsigned short*)cnt;     // cnt dead after cs pass 1
    int* partial = (int*)W2;                           // W2 dead after cs pass 2

    dim3 rb(256), rg(RGRID);                     // 800 blocks (float rotate passes)
    dim3 sbk(512);
    dim3 sg(SGRID);                              // 1000 blocks (plain sweeps)
    dim3 srg(SGRID + RGRID);                     // 1800 blocks (sweep + rotate)
    dim3 szg(SGRID + ZGRID);                     // 2000 blocks (sweep + zero)
    dim3 pb(256), pg(NVOX / 4 / 256);            // 4000 blocks (proba x4)

    // g1..g3: sweeps fused with the 3 independent cw int-rotate passes.
    // Buffers: sweeps ping-pong W2 -> W4 -> W2 (W4 = idle cnt region);
    // rotates data -> W1 -> W3 -> W1 (cwp ends in W1).
    sweep_rot_kernel<0><<<srg, sbk, 0, stream>>>(data, nullptr, (int*)W2,
                                                 data, (unsigned*)W1);       // g1 | rot1
    sweep_rot_kernel<1><<<srg, sbk, 0, stream>>>(nullptr, (int*)W2, W4,
                                                 W1, (unsigned*)W3);         // g2 | rot2
    sweep_rot_kernel<1><<<srg, sbk, 0, stream>>>(nullptr, W4, (int*)W2,
                                                 W3, (unsigned*)W1);         // g3 | rot3
    unsigned* cwp = (unsigned*)W1;               // original layout

    // g4: sweep fused with zeroing cnt (W4 dead after g3 read it).
    sweep_zero_kernel<<<szg, sbk, 0, stream>>>((int*)W2, (int*)W3, W4);      // g4

    // g5..g15: plain sweeps, W3 <-> W2 ping-pong (g15 ends in W2).
    for (int i = 0; i < 11; ++i) {
        const int* src = (i & 1) ? (int*)W2 : (int*)W3;
        int*       dst = (i & 1) ? (int*)W3 : (int*)W2;
        ccl_sweep_kernel<<<sg, sbk, 0, stream>>>(src, dst);
    }
    // g16: final sweep + component-size count into cnt (=W4, zeroed at g4).
    ccl_sweep_count_kernel<<<sg, sbk, 0, stream>>>((int*)W2, (int*)W3, cnt);
    int* lab = (int*)W3;                         // gen-16 labels

    // cs float box sums (pass 1 fuses lsize*valid gather; pass 3 fuses
    // finalize: cand + idx + histogram — cs never materialized)
    box_rot_f32_g_kernel<<<rg, rb, 0, stream>>>(lab, cnt, cwp, W2);
    box_rot_f32_kernel<<<rg, rb, 0, stream>>>(W2, W3);
    box_rot_fin_kernel<<<rg, rb, 0, stream>>>(W3, cwp, cand, idxbuf, partial);

    hist_reduce_kernel<<<dim3(16), dim3(256), 0, stream>>>(partial, hist);
    hist_post_kernel<<<1, 256, 0, stream>>>(hist, ph, Sv);
    proba_kernel<<<pg, pb, 0, stream>>>(idxbuf, ph, Sv, proba);
}

// Round 4
// 386.766 us; speedup vs baseline: 1.2481x; 1.0109x over previous
//
#include <hip/hip_runtime.h>
#include <cmath>

#define D 160
#define DD (D*D)          // 25600
#define NVOX (D*D*D)
#define BIGV (NVOX + 2)
#define NBINS 4096
#define HALF 16
#define RGRID 800         // rotate-pass blocks = DD/32, also hist partial count
#define SGRID 1000        // sweep blocks (512 thr, 8 cells/thread)
#define ZGRID 1000        // zero-cnt blocks fused into sweep 4
#define CGRID 800         // cand rider blocks fused into sweep 5

// ---------------------------------------------------------------------------
// Rotate box pass as a device block-function (512-thread mapping: 16 strips
// x 10 elems), so it can ride inside sweep launches as extra blocks.
// MODE 0: pack classes from raw float data. MODE 1: pass-through uint.
// Layout (a,b,c) c-contig -> filter along c -> write (c,a,b).
// ---------------------------------------------------------------------------
template<int MODE>
__device__ __forceinline__ void rot_block(
    const void* __restrict__ vin, unsigned* __restrict__ out, int bi, int tid)
{
    __shared__ unsigned tin[32][161];
    __shared__ unsigned filt[160][33];
    int L0 = bi * 32;
    size_t base = (size_t)L0 * D;

    if (MODE == 0) {
        const float4* s4 = (const float4*)((const float*)vin + base);
        for (int i = tid; i < 32 * (D / 4); i += 512) {
            float4 v = s4[i];
            int e = i * 4, r = e / D, c = e - r * D;
            float rr;
            rr = rintf(v.x); tin[r][c]   = (rr==0.f) | ((rr==1.f)?0x10000u:0u);
            rr = rintf(v.y); tin[r][c+1] = (rr==0.f) | ((rr==1.f)?0x10000u:0u);
            rr = rintf(v.z); tin[r][c+2] = (rr==0.f) | ((rr==1.f)?0x10000u:0u);
            rr = rintf(v.w); tin[r][c+3] = (rr==0.f) | ((rr==1.f)?0x10000u:0u);
        }
    } else {
        const uint4* s4 = (const uint4*)((const unsigned*)vin + base);
        for (int i = tid; i < 32 * (D / 4); i += 512) {
            uint4 v = s4[i];
            int e = i * 4, r = e / D, c = e - r * D;
            tin[r][c] = v.x; tin[r][c+1] = v.y; tin[r][c+2] = v.z; tin[r][c+3] = v.w;
        }
    }
    __syncthreads();

    {
        int r = tid & 31, s = tid >> 5;      // s in [0,16)
        int i0 = 10 * s;
        const unsigned* ln = tin[r];
        unsigned sum = 0u;
        int jlo = i0 - 16; if (jlo < 0) jlo = 0;
        int jhi = i0 + 15; if (jhi > D - 1) jhi = D - 1;
        for (int j = jlo; j <= jhi; ++j) sum += ln[j];
        #pragma unroll
        for (int k = 0; k < 10; ++k) {
            int i = i0 + k;
            filt[i][r] = sum;
            int add = i + 16, rem = i - 16;
            if (add <= D - 1) sum += ln[add];
            if (rem >= 0)     sum -= ln[rem];
        }
    }
    __syncthreads();

    int r = tid & 31;
    for (int c = (tid >> 5); c < D; c += 16)
        out[(size_t)c * DD + L0 + r] = filt[c][r];
}

// ---------------------------------------------------------------------------
// Rotate box filter, FLOAT path, pass 1: fuses the lsize*valid gather.
// ---------------------------------------------------------------------------
__global__ __launch_bounds__(256) void box_rot_f32_g_kernel(
    const int* __restrict__ lab, const int* __restrict__ cnt,
    const unsigned* __restrict__ cwp, float* __restrict__ out)
{
    __shared__ float tin[32][161];
    __shared__ float filt[160][33];
    int L0 = blockIdx.x * 32;
    size_t base = (size_t)L0 * D;

    const int4*  lab4 = (const int4*)(lab + base);
    const uint4* cw4  = (const uint4*)(cwp + base);
    for (int i = threadIdx.x; i < 32 * (D / 4); i += 256) {
        int4 l = lab4[i];
        uint4 cw = cw4[i];
        int e = i * 4, r = e / D, c = e - r * D;
        tin[r][c]   = (l.x != BIGV && (cw.x >> 16) > 100u) ? (float)cnt[l.x] : 0.f;
        tin[r][c+1] = (l.y != BIGV && (cw.y >> 16) > 100u) ? (float)cnt[l.y] : 0.f;
        tin[r][c+2] = (l.z != BIGV && (cw.z >> 16) > 100u) ? (float)cnt[l.z] : 0.f;
        tin[r][c+3] = (l.w != BIGV && (cw.w >> 16) > 100u) ? (float)cnt[l.w] : 0.f;
    }
    __syncthreads();

    {
        int r = threadIdx.x & 31, s = threadIdx.x >> 5;
        int i0 = 20 * s;
        const float* ln = tin[r];
        float sum = 0.f;
        int jlo = i0 - 16; if (jlo < 0) jlo = 0;
        int jhi = i0 + 15; if (jhi > D - 1) jhi = D - 1;
        for (int j = jlo; j <= jhi; ++j) sum += ln[j];
        #pragma unroll 4
        for (int k = 0; k < 20; ++k) {
            int i = i0 + k;
            filt[i][r] = sum;
            int add = i + 16, rem = i - 16;
            if (add <= D - 1) sum += ln[add];
            if (rem >= 0)     sum -= ln[rem];
        }
    }
    __syncthreads();

    int r = threadIdx.x & 31;
    for (int c = (threadIdx.x >> 5); c < D; c += 8)
        out[(size_t)c * DD + L0 + r] = filt[c][r];
}

// plain float middle pass
__global__ __launch_bounds__(256) void box_rot_f32_kernel(
    const float* __restrict__ fin, float* __restrict__ out)
{
    __shared__ float tin[32][161];
    __shared__ float filt[160][33];
    int L0 = blockIdx.x * 32;
    size_t base = (size_t)L0 * D;

    const float4* s4 = (const float4*)(fin + base);
    for (int i = threadIdx.x; i < 32 * (D / 4); i += 256) {
        float4 v = s4[i];
        int e = i * 4, r = e / D, c = e - r * D;
        tin[r][c] = v.x; tin[r][c+1] = v.y; tin[r][c+2] = v.z; tin[r][c+3] = v.w;
    }
    __syncthreads();

    {
        int r = threadIdx.x & 31, s = threadIdx.x >> 5;
        int i0 = 20 * s;
        const float* ln = tin[r];
        float sum = 0.f;
        int jlo = i0 - 16; if (jlo < 0) jlo = 0;
        int jhi = i0 + 15; if (jhi > D - 1) jhi = D - 1;
        for (int j = jlo; j <= jhi; ++j) sum += ln[j];
        #pragma unroll 4
        for (int k = 0; k < 20; ++k) {
            int i = i0 + k;
            filt[i][r] = sum;
            int add = i + 16, rem = i - 16;
            if (add <= D - 1) sum += ln[add];
            if (rem >= 0)     sum -= ln[rem];
        }
    }
    __syncthreads();

    int r = threadIdx.x & 31;
    for (int c = (threadIdx.x >> 5); c < D; c += 8)
        out[(size_t)c * DD + L0 + r] = filt[c][r];
}

// ---------------------------------------------------------------------------
// cs pass 3 fused with finalize: idx + LDS histogram. (cand is now produced
// by the g5 rider — fin re-derives cd from cwp it already reads, and no
// longer stores the 16.4 MB cand stream in the serial tail.)
// ---------------------------------------------------------------------------
__global__ __launch_bounds__(256) void box_rot_fin_kernel(
    const float* __restrict__ fin, const unsigned* __restrict__ cwp,
    unsigned short* __restrict__ idxbuf, int* __restrict__ partial)
{
    __shared__ float tin[32][161];
    __shared__ float filt[160][33];
    __shared__ int lh[NBINS];
    for (int i = threadIdx.x; i < NBINS; i += 256) lh[i] = 0;

    int L0 = blockIdx.x * 32;
    size_t base = (size_t)L0 * D;
    const float4* s4 = (const float4*)(fin + base);
    for (int i = threadIdx.x; i < 32 * (D / 4); i += 256) {
        float4 v = s4[i];
        int e = i * 4, r = e / D, c = e - r * D;
        tin[r][c] = v.x; tin[r][c+1] = v.y; tin[r][c+2] = v.z; tin[r][c+3] = v.w;
    }
    __syncthreads();

    {
        int r = threadIdx.x & 31, s = threadIdx.x >> 5;
        int i0 = 20 * s;
        const float* ln = tin[r];
        float sum = 0.f;
        int jlo = i0 - 16; if (jlo < 0) jlo = 0;
        int jhi = i0 + 15; if (jhi > D - 1) jhi = D - 1;
        for (int j = jlo; j <= jhi; ++j) sum += ln[j];
        #pragma unroll 4
        for (int k = 0; k < 20; ++k) {
            int i = i0 + k;
            filt[i][r] = sum;
            int add = i + 16, rem = i - 16;
            if (add <= D - 1) sum += ln[add];
            if (rem >= 0)     sum -= ln[rem];
        }
    }
    __syncthreads();

    int r = threadIdx.x & 31;
    int L = L0 + r;
    int y = L / D, z = L - (L / D) * D;
    bool byz = (y >= HALF && y < D - HALF && z >= HALF && z < D - HALF);
    int wy = min(y + 15, D - 1) - max(y - 16, 0) + 1;
    int wz = min(z + 15, D - 1) - max(z - 16, 0) + 1;
    for (int c = (threadIdx.x >> 5); c < D; c += 8) {   // c == x
        int p = c * DD + L;
        unsigned pk = cwp[p];
        unsigned cw0 = pk & 0xFFFFu;
        unsigned cw1 = pk >> 16;
        int wx = min(c + 15, D - 1) - max(c - 16, 0) + 1;
        unsigned cw2 = (unsigned)(wx * wy * wz) - cw0 - cw1;
        float v0 = (cw0 > 100u) ? 1.f : 0.f;
        float v1 = (cw1 > 100u) ? 1.f : 0.f;
        float v2 = (cw2 > 100u) ? 1.f : 0.f;
        float border = (byz && c >= HALF && c < D - HALF) ? 1.f : 0.f;
        float cd = (border * v1 + v0 + v2 >= 2.f) ? 1.f : 0.f;
        float mean = (cw1 > 0u) ? filt[c][r] / fmaxf((float)cw1, 1.f) : 0.f;
        int idx = (int)rintf(cd * mean);    // round half-to-even == jnp.round
        idx = min(max(idx, 0), NBINS - 1);
        idxbuf[p] = (unsigned short)idx;
        if (idx != 0) atomicAdd(&lh[idx], 1);   // hist[0] never consumed
    }
    __syncthreads();
    int* po = partial + blockIdx.x * NBINS;
    for (int i = threadIdx.x; i < NBINS; i += 256) po[i] = lh[i];
}

// ---------------------------------------------------------------------------
// CCL: 16 single-generation sweeps (R2: 2-gen register fusion = 2.8x a
// sweep, loses; 16 launches is the structure). R3 calibration: each launch
// slot costs ~6us wall beyond traffic -> fuse independent work into idle
// sweep launches (g1-g3: cw rotate passes; g4: cnt+ticket zeroing; g5:
// cand computation, which depends only on cwp).
// XCD swizzle: each XCD owns a contiguous 20-plane x-slab.
// ---------------------------------------------------------------------------
__device__ __forceinline__ int min6(int c, int a, int b, int d, int e, int f, int g) {
    if (c == BIGV) return BIGV;
    return min(min(min(c, a), min(b, d)), min(min(e, f), g));
}

__device__ __forceinline__ int4 min7_run(int4 c, int lm, int rm,
                                         int4 ym, int4 yp, int4 xm, int4 xp) {
    int4 o;
    o.x = min6(c.x, lm,  c.y, ym.x, yp.x, xm.x, xp.x);
    o.y = min6(c.y, c.x, c.z, ym.y, yp.y, xm.y, xp.y);
    o.z = min6(c.z, c.y, c.w, ym.z, yp.z, xm.z, xp.z);
    o.w = min6(c.w, c.z, rm,  ym.w, yp.w, xm.w, xp.w);
    return o;
}

__device__ __forceinline__ void wave_count(int l, int lane, int* __restrict__ cnt) {
    unsigned long long remaining = __ballot(l != BIGV);
    while (remaining) {
        int leader = __ffsll((unsigned long long)remaining) - 1;
        int ll = __shfl(l, leader, 64);
        unsigned long long mm = __ballot(l == ll);
        if (lane == leader) atomicAdd(&cnt[ll], (int)__popcll(mm & remaining));
        remaining &= ~mm;
    }
}

__device__ __forceinline__ int4 cls4(float4 v, int p0) {
    int4 l;
    l.x = (rintf(v.x) == 1.f) ? (p0 + 1) : BIGV;
    l.y = (rintf(v.y) == 1.f) ? (p0 + 2) : BIGV;
    l.z = (rintf(v.z) == 1.f) ? (p0 + 3) : BIGV;
    l.w = (rintf(v.w) == 1.f) ? (p0 + 4) : BIGV;
    return l;
}

struct LabLd {
    const int* __restrict__ a;
    __device__ __forceinline__ int4 v(int p) const { return ((const int4*)a)[p >> 2]; }
    __device__ __forceinline__ int  s(int p) const { return a[p]; }
};
struct DataLd {
    const float* __restrict__ a;
    __device__ __forceinline__ int4 v(int p) const { return cls4(((const float4*)a)[p >> 2], p); }
    __device__ __forceinline__ int  s(int p) const { return (rintf(a[p]) == 1.f) ? (p + 1) : BIGV; }
};

template<typename LDT, int COUNT>
__device__ __forceinline__ void sweep_block(
    LDT ld, int* __restrict__ outp, int* __restrict__ cnt, int b, int tid)
{
    const int4 BIG4 = make_int4(BIGV, BIGV, BIGV, BIGV);
    int sb = (b & 7) * (SGRID / 8) + (b >> 3);   // XCD-contiguous x-slab
    int lane = tid & 63;
    int wv   = tid >> 6;
    int wbase = sb * 4096 + wv * 512;
    int pA = wbase + 4 * lane;
    int pB = pA + 256;

    int4 cA = ld.v(pA), cB = ld.v(pB);

    int zA = pA % D, zB = pB % D;
    int lmA = __shfl_up(cA.w, 1);
    int rmA = __shfl_down(cA.x, 1);
    int lmB = __shfl_up(cB.w, 1);
    int rmB = __shfl_down(cB.x, 1);
    int stA = __shfl(cB.x, 0, 64);   // voxel wbase+256 (A.lane63 right nbr)
    int stB = __shfl(cA.w, 63, 64);  // voxel wbase+255 (B.lane0 left nbr)
    if (lane == 63) rmA = stA;
    if (lane == 0)  lmB = stB;
    if (zA == 0)          lmA = BIGV;
    else if (lane == 0)   lmA = ld.s(pA - 1);
    if (zA == D - 4)      rmA = BIGV;
    if (zB == 0)          lmB = BIGV;
    if (zB == D - 4)      rmB = BIGV;
    else if (lane == 63)  rmB = ld.s(pB + 4);

    int rA = pA / D, yA = rA % D, xA = rA / D;
    int4 ylA = (yA > 0)     ? ld.v(pA - D)  : BIG4;
    int4 yhA = (yA < D - 1) ? ld.v(pA + D)  : BIG4;
    int4 xlA = (xA > 0)     ? ld.v(pA - DD) : BIG4;
    int4 xhA = (xA < D - 1) ? ld.v(pA + DD) : BIG4;
    int4 oA = min7_run(cA, lmA, rmA, ylA, yhA, xlA, xhA);

    int rB = pB / D, yB = rB % D, xB = rB / D;
    int4 ylB = (yB > 0)     ? ld.v(pB - D)  : BIG4;
    int4 yhB = (yB < D - 1) ? ld.v(pB + D)  : BIG4;
    int4 xlB = (xB > 0)     ? ld.v(pB - DD) : BIG4;
    int4 xhB = (xB < D - 1) ? ld.v(pB + DD) : BIG4;
    int4 oB = min7_run(cB, lmB, rmB, ylB, yhB, xlB, xhB);

    int4* out4 = (int4*)outp;
    out4[pA >> 2] = oA; out4[pB >> 2] = oB;

    if (COUNT) {   // final generation: component-size count from registers
        wave_count(oA.x, lane, cnt);
        wave_count(oA.y, lane, cnt);
        wave_count(oA.z, lane, cnt);
        wave_count(oA.w, lane, cnt);
        wave_count(oB.x, lane, cnt);
        wave_count(oB.y, lane, cnt);
        wave_count(oB.z, lane, cnt);
        wave_count(oB.w, lane, cnt);
    }
}

// plain sweeps (g6..g15)
__global__ __launch_bounds__(512) void ccl_sweep_kernel(
    const int* __restrict__ lab, int* __restrict__ outp)
{
    LabLd ld{lab};
    sweep_block<LabLd, 0>(ld, outp, nullptr, blockIdx.x, threadIdx.x);
}

// final sweep (g16) + component-size count
__global__ __launch_bounds__(512) void ccl_sweep_count_kernel(
    const int* __restrict__ lab, int* __restrict__ outp, int* __restrict__ cnt)
{
    LabLd ld{lab};
    sweep_block<LabLd, 1>(ld, outp, cnt, blockIdx.x, threadIdx.x);
}

// sweep + rotate pass fused (g1..g3). MODE0: sweep from data + rot pass1
// (pack classes from data). MODE1: sweep from labels + rot pass-through.
template<int MODE>
__global__ __launch_bounds__(512) void sweep_rot_kernel(
    const float* __restrict__ data, const int* __restrict__ labsrc,
    int* __restrict__ swdst,
    const void* __restrict__ rin, unsigned* __restrict__ rout)
{
    if ((int)blockIdx.x < SGRID) {
        if (MODE == 0) {
            DataLd ld{data};
            sweep_block<DataLd, 0>(ld, swdst, nullptr, blockIdx.x, threadIdx.x);
        } else {
            LabLd ld{labsrc};
            sweep_block<LabLd, 0>(ld, swdst, nullptr, blockIdx.x, threadIdx.x);
        }
    } else {
        rot_block<MODE>(rin, rout, blockIdx.x - SGRID, threadIdx.x);
    }
}

// sweep g4 + zero the cnt region and the hist ticket (W4 dead after g3 read
// it; must be zero before g16's atomics). Replaces the upfront memset.
__global__ __launch_bounds__(512) void sweep_zero_kernel(
    const int* __restrict__ labsrc, int* __restrict__ swdst,
    int* __restrict__ zbuf, int* __restrict__ ticket)
{
    if ((int)blockIdx.x < SGRID) {
        LabLd ld{labsrc};
        sweep_block<LabLd, 0>(ld, swdst, nullptr, blockIdx.x, threadIdx.x);
    } else {
        int zb = blockIdx.x - SGRID;                 // 0..ZGRID-1
        int t = (zb * 512 + threadIdx.x) * 2;        // int4 units
        const int4 z4 = make_int4(0, 0, 0, 0);
        ((int4*)zbuf)[t] = z4; ((int4*)zbuf)[t + 1] = z4;   // 1000*512*8 = NVOX ints
        if (zb == 0 && threadIdx.x == 0) { zbuf[NVOX] = 0; ticket[0] = 0; }
    }
}

// sweep g5 + cand rider: candidates depend only on cwp (ready after g3).
// Rider writes the final cand output stream during otherwise-idle sweep
// time; box_rot_fin then re-derives cd locally without storing it.
__global__ __launch_bounds__(512) void sweep_cand_kernel(
    const int* __restrict__ labsrc, int* __restrict__ swdst,
    const unsigned* __restrict__ cwp, float* __restrict__ cand)
{
    if ((int)blockIdx.x < SGRID) {
        LabLd ld{labsrc};
        sweep_block<LabLd, 0>(ld, swdst, nullptr, blockIdx.x, threadIdx.x);
        return;
    }
    int t0 = (blockIdx.x - SGRID) * 512 + threadIdx.x;
    const uint4* cw4 = (const uint4*)cwp;
    float4* c4 = (float4*)cand;
    for (int q = t0; q < NVOX / 4; q += CGRID * 512) {
        int p0 = q * 4;
        int z0 = p0 % D;
        int r  = p0 / D;
        int y  = r % D;
        int x  = r / D;
        int wy = min(y + 15, D - 1) - max(y - 16, 0) + 1;
        int wx = min(x + 15, D - 1) - max(x - 16, 0) + 1;
        bool bxy = (y >= HALF && y < D - HALF && x >= HALF && x < D - HALF);
        uint4 pk = cw4[q];
        float4 o;
        {
            unsigned c0 = pk.x & 0xFFFFu, c1 = pk.x >> 16;
            int z = z0, wz = min(z + 15, D - 1) - max(z - 16, 0) + 1;
            unsigned c2 = (unsigned)(wx * wy * wz) - c0 - c1;
            float v0 = (c0 > 100u) ? 1.f : 0.f, v1 = (c1 > 100u) ? 1.f : 0.f, v2 = (c2 > 100u) ? 1.f : 0.f;
            float border = (bxy && z >= HALF && z < D - HALF) ? 1.f : 0.f;
            o.x = (border * v1 + v0 + v2 >= 2.f) ? 1.f : 0.f;
        }
        {
            unsigned c0 = pk.y & 0xFFFFu, c1 = pk.y >> 16;
            int z = z0 + 1, wz = min(z + 15, D - 1) - max(z - 16, 0) + 1;
            unsigned c2 = (unsigned)(wx * wy * wz) - c0 - c1;
            float v0 = (c0 > 100u) ? 1.f : 0.f, v1 = (c1 > 100u) ? 1.f : 0.f, v2 = (c2 > 100u) ? 1.f : 0.f;
            float border = (bxy && z >= HALF && z < D - HALF) ? 1.f : 0.f;
            o.y = (border * v1 + v0 + v2 >= 2.f) ? 1.f : 0.f;
        }
        {
            unsigned c0 = pk.z & 0xFFFFu, c1 = pk.z >> 16;
            int z = z0 + 2, wz = min(z + 15, D - 1) - max(z - 16, 0) + 1;
            unsigned c2 = (unsigned)(wx * wy * wz) - c0 - c1;
            float v0 = (c0 > 100u) ? 1.f : 0.f, v1 = (c1 > 100u) ? 1.f : 0.f, v2 = (c2 > 100u) ? 1.f : 0.f;
            float border = (bxy && z >= HALF && z < D - HALF) ? 1.f : 0.f;
            o.z = (border * v1 + v0 + v2 >= 2.f) ? 1.f : 0.f;
        }
        {
            unsigned c0 = pk.w & 0xFFFFu, c1 = pk.w >> 16;
            int z = z0 + 3, wz = min(z + 15, D - 1) - max(z - 16, 0) + 1;
            unsigned c2 = (unsigned)(wx * wy * wz) - c0 - c1;
            float v0 = (c0 > 100u) ? 1.f : 0.f, v1 = (c1 > 100u) ? 1.f : 0.f, v2 = (c2 > 100u) ? 1.f : 0.f;
            float border = (bxy && z >= HALF && z < D - HALF) ? 1.f : 0.f;
            o.w = (border * v1 + v0 + v2 >= 2.f) ? 1.f : 0.f;
        }
        c4[q] = o;
    }
}

// ---------------------------------------------------------------------------
// hist reduce + post fused via last-block ticket (no spinning — safe under
// undefined dispatch order). Agent-scope atomics for cross-XCD hist
// visibility; ticket zeroed each graph iteration by g4's zero-rider.
// ---------------------------------------------------------------------------
__global__ __launch_bounds__(256) void hist_rp_kernel(
    const int* __restrict__ partial, int* __restrict__ hist,
    float* __restrict__ ph_full, float* __restrict__ Sout,
    int* __restrict__ ticket)
{
    int t = threadIdx.x;
    int bin = blockIdx.x * 256 + t;     // 16 x 256 = 4096
    int s = 0;
    #pragma unroll 4
    for (int b = 0; b < RGRID; ++b) s += partial[b * NBINS + bin];
    __hip_atomic_store(&hist[bin], s, __ATOMIC_RELAXED, __HIP_MEMORY_SCOPE_AGENT);
    __threadfence();
    __syncthreads();
    __shared__ int lastblk;
    if (t == 0) lastblk = (atomicAdd(ticket, 1) == gridDim.x - 1) ? 1 : 0;
    __syncthreads();
    if (!lastblk) return;

    // ---- post phase (one block), bit-identical arithmetic to hist_post ----
    __shared__ float red[256];
    int hv[16];
    #pragma unroll
    for (int k = 0; k < 16; ++k)
        hv[k] = __hip_atomic_load(&hist[t + k * 256], __ATOMIC_RELAXED,
                                  __HIP_MEMORY_SCOPE_AGENT);

    float loc = 0.f;
    #pragma unroll
    for (int k = 0; k < 16; ++k) {
        int b = t + k * 256;
        if (b >= 1) loc += (float)hv[k];
    }
    red[t] = loc; __syncthreads();
    for (int o = 128; o > 0; o >>= 1) { if (t < o) red[t] += red[t + o]; __syncthreads(); }
    float numb = red[0]; __syncthreads();

    float rv[16];
    loc = 0.f;
    #pragma unroll
    for (int k = 0; k < 16; ++k) {
        int b = t + k * 256;
        float r = 0.f;
        if (b >= 1) {
            int h = hv[k];
            if (h > 0) r = numb / (float)h;
        }
        rv[k] = r;
        loc += r;
    }
    red[t] = loc; __syncthreads();
    for (int o = 128; o > 0; o >>= 1) { if (t < o) red[t] += red[t + o]; __syncthreads(); }
    float sumrec = red[0]; __syncthreads();
    float inv_sumrec = (sumrec > 0.f) ? 1.f / sumrec : 0.f;

    loc = 0.f;
    #pragma unroll
    for (int k = 0; k < 16; ++k) {
        int b = t + k * 256;
        float ph = (b >= 1) ? rv[k] * inv_sumrec : 0.f;
        ph_full[b] = ph;
        loc += ph * (float)hv[k];
    }
    red[t] = loc; __syncthreads();
    for (int o = 128; o > 0; o >>= 1) { if (t < o) red[t] += red[t + o]; __syncthreads(); }
    if (t == 0) Sout[0] = (red[0] > 0.f) ? red[0] : 1.f;
}

__global__ __launch_bounds__(256) void proba_kernel(
    const unsigned short* __restrict__ idxbuf,
    const float* __restrict__ ph_full, const float* __restrict__ Sv,
    float* __restrict__ outp)
{
    int t = blockIdx.x * blockDim.x + threadIdx.x;   // exact grid NVOX/4
    ushort4 i4 = ((const ushort4*)idxbuf)[t];
    float inv = 1.f / Sv[0];
    float4 o;
    o.x = ph_full[i4.x] * inv;
    o.y = ph_full[i4.y] * inv;
    o.z = ph_full[i4.z] * inv;
    o.w = ph_full[i4.w] * inv;
    ((float4*)outp)[t] = o;
}

// ---------------------------------------------------------------------------
extern "C" void kernel_launch(void* const* d_in, const int* in_sizes, int n_in,
                              void* d_out, int out_size, void* d_ws, size_t ws_size,
                              hipStream_t stream)
{
    const float* data = (const float*)d_in[0];
    float* out   = (float*)d_out;
    float* cand  = out;
    float* proba = out + NVOX;

    char* ws = (char*)d_ws;
    const size_t NB = (size_t)NVOX * sizeof(float);
    float* W1 = (float*)(ws);
    float* W2 = (float*)(ws + NB);
    float* W3 = (float*)(ws + 2 * NB);
    int*   W4 = (int*)(ws + 3 * NB);                   // cnt region / 3rd ping-pong buf
    int*   cnt  = W4;                                  // NVOX+1 ints (last int in pad)
    float* ph   = (float*)(ws + 4 * NB + 16);
    int*   hist = (int*)  (ws + 4 * NB + 16 + NBINS * 4);
    float* Sv   = (float*)(ws + 4 * NB + 16 + 2 * NBINS * 4);
    int*   ticket = (int*)(ws + 4 * NB + 16 + 2 * NBINS * 4 + 8);
    unsigned short* idxbuf = (unsigned short*)cnt;     // cnt dead after cs pass 1
    int* partial = (int*)W2;                           // W2 dead after cs pass 2

    dim3 rb(256), rg(RGRID);                     // 800 blocks (float rotate passes)
    dim3 sbk(512);
    dim3 sg(SGRID);                              // 1000 blocks (plain sweeps)
    dim3 srg(SGRID + RGRID);                     // 1800 blocks (sweep + rotate)
    dim3 szg(SGRID + ZGRID);                     // 2000 blocks (sweep + zero)
    dim3 scg(SGRID + CGRID);                     // 1800 blocks (sweep + cand)
    dim3 pb(256), pg(NVOX / 4 / 256);            // 4000 blocks (proba x4)

    // g1..g3: sweeps fused with the 3 independent cw int-rotate passes.
    // Sweeps ping-pong W2 -> W4 -> W2 (W4 = idle cnt region); rotates
    // data -> W1 -> W3 -> W1 (cwp ends in W1).
    sweep_rot_kernel<0><<<srg, sbk, 0, stream>>>(data, nullptr, (int*)W2,
                                                 data, (unsigned*)W1);       // g1 | rot1
    sweep_rot_kernel<1><<<srg, sbk, 0, stream>>>(nullptr, (int*)W2, W4,
                                                 W1, (unsigned*)W3);         // g2 | rot2
    sweep_rot_kernel<1><<<srg, sbk, 0, stream>>>(nullptr, W4, (int*)W2,
                                                 W3, (unsigned*)W1);         // g3 | rot3
    unsigned* cwp = (unsigned*)W1;               // original layout

    // g4: sweep fused with zeroing cnt + ticket (W4 dead after g3 read it).
    sweep_zero_kernel<<<szg, sbk, 0, stream>>>((int*)W2, (int*)W3, W4, ticket); // g4

    // g5: sweep fused with the cand rider (cand = f(cwp) only).
    sweep_cand_kernel<<<scg, sbk, 0, stream>>>((int*)W3, (int*)W2, cwp, cand);  // g5

    // g6..g15: plain sweeps, W2 <-> W3 ping-pong (g15 ends in W2).
    for (int i = 0; i < 10; ++i) {
        const int* src = (i & 1) ? (int*)W3 : (int*)W2;
        int*       dst = (i & 1) ? (int*)W2 : (int*)W3;
        ccl_sweep_kernel<<<sg, sbk, 0, stream>>>(src, dst);
    }
    // g16: final sweep + component-size count into cnt (=W4, zeroed at g4).
    ccl_sweep_count_kernel<<<sg, sbk, 0, stream>>>((int*)W2, (int*)W3, cnt);
    int* lab = (int*)W3;                         // gen-16 labels

    // cs float box sums (pass 1 fuses lsize*valid gather; pass 3 fuses
    // finalize: idx + histogram — cs and cd never materialized here)
    box_rot_f32_g_kernel<<<rg, rb, 0, stream>>>(lab, cnt, cwp, W2);
    box_rot_f32_kernel<<<rg, rb, 0, stream>>>(W2, W3);
    box_rot_fin_kernel<<<rg, rb, 0, stream>>>(W3, cwp, idxbuf, partial);

    hist_rp_kernel<<<dim3(16), dim3(256), 0, stream>>>(partial, hist, ph, Sv, ticket);
    proba_kernel<<<pg, pb, 0, stream>>>(idxbuf, ph, Sv, proba);
}